// Round 1
// baseline (325.709 us; speedup 1.0000x reference)
//
#include <hip/hip_runtime.h>

// Problem constants (match reference)
constexpr int BB = 2;
constexpr int DD = 128;   // MAXDISP
constexpr int HH = 384;
constexpr int WW = 768;
constexpr int W4 = WW / 4;                 // 192 float4 per row
constexpr int TOTAL4 = BB * DD * HH * W4;  // 18,874,368 float4 outputs

__global__ __launch_bounds__(256) void Hamming_34205119545967_kernel(
    const int* __restrict__ img1, const int* __restrict__ img2,
    const float* __restrict__ scale, float* __restrict__ out) {
    int i = blockIdx.x * blockDim.x + threadIdx.x;  // index in float4 units
    if (i >= TOTAL4) return;

    int x4  = i % W4;
    int row = i / W4;          // row = (b*DD + d)*HH + h
    int h   = row % HH;
    int bd  = row / HH;
    int d   = bd % DD;
    int b   = bd / DD;
    int x   = x4 * 4;

    const int* __restrict__ l_row = img1 + ((size_t)b * HH + h) * WW;
    const int* __restrict__ r_row = img2 + ((size_t)b * HH + h) * WW;

    int4 r = *reinterpret_cast<const int4*>(r_row + x);
    float s = scale[0];

    int off = x + d;
    // clamped loads (reference uses jnp.minimum(off, W-1)); stay in-bounds
    int l0 = l_row[min(off + 0, WW - 1)];
    int l1 = l_row[min(off + 1, WW - 1)];
    int l2 = l_row[min(off + 2, WW - 1)];
    int l3 = l_row[min(off + 3, WW - 1)];

    float4 o;
    o.x = (off + 0 < WW) ? (float)__popc(l0 ^ r.x) * s : 0.0f;
    o.y = (off + 1 < WW) ? (float)__popc(l1 ^ r.y) * s : 0.0f;
    o.z = (off + 2 < WW) ? (float)__popc(l2 ^ r.z) * s : 0.0f;
    o.w = (off + 3 < WW) ? (float)__popc(l3 ^ r.w) * s : 0.0f;

    reinterpret_cast<float4*>(out)[i] = o;
}

extern "C" void kernel_launch(void* const* d_in, const int* in_sizes, int n_in,
                              void* d_out, int out_size, void* d_ws, size_t ws_size,
                              hipStream_t stream) {
    const int*   img1  = (const int*)d_in[0];
    const int*   img2  = (const int*)d_in[1];
    const float* scale = (const float*)d_in[2];
    float*       out   = (float*)d_out;

    constexpr int block = 256;
    constexpr int grid  = (TOTAL4 + block - 1) / block;  // 73728 blocks
    Hamming_34205119545967_kernel<<<grid, block, 0, stream>>>(img1, img2, scale, out);
}

// Round 2
// 303.780 us; speedup vs baseline: 1.0722x; 1.0722x over previous
//
#include <hip/hip_runtime.h>

// Problem constants (match reference)
constexpr int BB = 2;
constexpr int DD = 128;   // MAXDISP
constexpr int HH = 384;
constexpr int WW = 768;
constexpr int W4 = WW / 4;                 // 192 int4/float4 per row

__global__ __launch_bounds__(192) void Hamming_34205119545967_kernel(
    const int* __restrict__ img1, const int* __restrict__ img2,
    const float* __restrict__ scale, float* __restrict__ out) {
    // grid: (HH, DD, BB) -> no integer division anywhere
    const int h = blockIdx.x;
    const int d = blockIdx.y;
    const int b = blockIdx.z;
    const int x4 = threadIdx.x;            // 0..191, one float4 of output each

    const int4* __restrict__ L4 =
        reinterpret_cast<const int4*>(img1 + ((size_t)b * HH + h) * WW);
    const int4* __restrict__ R4 =
        reinterpret_cast<const int4*>(img2 + ((size_t)b * HH + h) * WW);

    // right word: aligned, coalesced
    const int4 r = R4[x4];

    // left window: two aligned int4 loads covering words [4*(x4+q) .. 4*(x4+q)+7],
    // then pick 4 consecutive words starting at rm = d&3 (rm is wave-uniform).
    const int q  = d >> 2;
    const int rm = d & 3;
    const int ia = min(x4 + q,     W4 - 1);   // clamp like jnp.minimum; clamped
    const int ib = min(x4 + q + 1, W4 - 1);   // lanes are zeroed by `valid` below
    const int4 A = L4[ia];
    const int4 B = L4[ib];

    int w0, w1, w2, w3;
    switch (rm) {   // uniform per block -> scalar branch, no divergence
        case 0:  w0 = A.x; w1 = A.y; w2 = A.z; w3 = A.w; break;
        case 1:  w0 = A.y; w1 = A.z; w2 = A.w; w3 = B.x; break;
        case 2:  w0 = A.z; w1 = A.w; w2 = B.x; w3 = B.y; break;
        default: w0 = A.w; w1 = B.x; w2 = B.y; w3 = B.z; break;
    }

    const float s  = scale[0];
    const int  off = (x4 << 2) + d;
    float4 o;
    o.x = (off + 0 < WW) ? (float)__popc(w0 ^ r.x) * s : 0.0f;
    o.y = (off + 1 < WW) ? (float)__popc(w1 ^ r.y) * s : 0.0f;
    o.z = (off + 2 < WW) ? (float)__popc(w2 ^ r.z) * s : 0.0f;
    o.w = (off + 3 < WW) ? (float)__popc(w3 ^ r.w) * s : 0.0f;

    float4* __restrict__ orow =
        reinterpret_cast<float4*>(out + (((size_t)b * DD + d) * HH + h) * WW);
    orow[x4] = o;
}

extern "C" void kernel_launch(void* const* d_in, const int* in_sizes, int n_in,
                              void* d_out, int out_size, void* d_ws, size_t ws_size,
                              hipStream_t stream) {
    const int*   img1  = (const int*)d_in[0];
    const int*   img2  = (const int*)d_in[1];
    const float* scale = (const float*)d_in[2];
    float*       out   = (float*)d_out;

    dim3 grid(HH, DD, BB);   // 384 x 128 x 2 = 98304 blocks
    dim3 block(192);         // one row of 192 float4 per block (3 waves)
    Hamming_34205119545967_kernel<<<grid, block, 0, stream>>>(img1, img2, scale, out);
}